// Round 1
// baseline (503.213 us; speedup 1.0000x reference)
//
#include <hip/hip_runtime.h>
#include <math.h>
#include <stdint.h>

// KWinners: per-row top-K binary mask with duty-cycle boosting.
// x: (4096, 16384) fp32, duty: (16384,) fp32, out: (4096, 16384) fp32 0/1 mask.
//
// Round-3 design (register-resident khi + ballot counting):
//  - khi (top 16 bits of order-preserving key) kept in 16 VGPRs per thread
//    (uint2 kh[8], statically indexed) -- no 32 KB LDS array, no LDS
//    write+2x-read round trips. LDS drops to ~17 KB/block.
//  - Probe counting via __popcll(__ballot(h > P)): 1 v_cmp per term instead
//    of cmp+add per lane; counts are wave-uniform scalars, so the shuffle
//    reduction disappears (lane 0 writes the wave count directly).
//  - Probe key prefixes constant-folded at compile time.
//  - Bulk mask write fused with candidate gather (single unpack pass).
//  - Refinement loop recounts from registers; serial radix fallback
//    recomputes keys from x. Exact for ANY input.

#define N_UNITS 16384
#define K_WIN 655
#define NT 512
#define NPROBE 11
#define CAP 2048
#define ITERS (N_UNITS / (NT * 4))  // 8

// Order-preserving float -> uint map: larger float => larger key.
__device__ __forceinline__ uint32_t fkey(float f) {
    uint32_t b = __float_as_uint(f);
    uint32_t m = (uint32_t)((int32_t)b >> 31) | 0x80000000u;
    return b ^ m;
}

__global__ void boost_kernel(const float* __restrict__ duty,
                             float* __restrict__ bf, int n) {
    int i = blockIdx.x * blockDim.x + threadIdx.x;
    if (i < n) {
        const float td = 0.03997802734375f;  // 655/16384, exact in fp32
        float s = td - duty[i];              // fp32 subtract, matches ref
        bf[i] = (float)exp((double)s);       // correctly-rounded fp32 exp
    }
}

__global__ __launch_bounds__(NT, 6) void kwinners_kernel(
    const float* __restrict__ x, const float* __restrict__ bf,
    float* __restrict__ out) {
    __shared__ uint32_t red[(NT / 64) * NPROBE];  // per-wave counts
    __shared__ int cglob[NPROBE];
    __shared__ int prb[NPROBE];
    __shared__ uint32_t cand_idx[CAP];  // 8 KB
    __shared__ uint32_t cand_key[CAP];  // 8 KB
    __shared__ int sc[1];               // candidate count

    const int tid = threadIdx.x;
    const int lane = tid & 63;
    const int w = tid >> 6;
    const int row = blockIdx.x;
    const float4* xrow = (const float4*)(x + (size_t)row * N_UNITS);
    const float4* bfv = (const float4*)bf;
    float* orow = out + (size_t)row * N_UNITS;

    if (tid == 0) sc[0] = 0;  // ordered before atomics by the reduce barrier

    // Probes tuned for N(0,1)*boost; fkey(literal) constant-folds.
    int P[NPROBE];
    {
        const float pv[NPROBE] = {1.90f, 1.70f, 1.55f, 1.43f, 1.33f, 1.25f,
                                  1.18f, 1.12f, 1.06f, 0.99f, 0.90f};
#pragma unroll
        for (int p = 0; p < NPROBE; ++p) P[p] = (int)(fkey(pv[p]) >> 16);
    }

    int cnt[NPROBE];
#pragma unroll
    for (int p = 0; p < NPROBE; ++p) cnt[p] = 0;

    uint2 kh[ITERS];  // khi for this thread's 32 elements (16 VGPRs)

    // ---- fused: global load -> keys -> khi in regs + ballot counting ----
#pragma unroll
    for (int j = 0; j < ITERS; ++j) {
        int i4 = tid + j * NT;
        float4 xv = xrow[i4];
        float4 bv = bfv[i4];
        int h0 = (int)(fkey(xv.x * bv.x) >> 16);
        int h1 = (int)(fkey(xv.y * bv.y) >> 16);
        int h2 = (int)(fkey(xv.z * bv.z) >> 16);
        int h3 = (int)(fkey(xv.w * bv.w) >> 16);
        kh[j].x = (uint32_t)h0 | ((uint32_t)h1 << 16);
        kh[j].y = (uint32_t)h2 | ((uint32_t)h3 << 16);
#pragma unroll
        for (int p = 0; p < NPROBE; ++p)
            cnt[p] += __popcll(__ballot(h0 > P[p])) +
                      __popcll(__ballot(h1 > P[p])) +
                      __popcll(__ballot(h2 > P[p])) +
                      __popcll(__ballot(h3 > P[p]));
    }

    // ---- block reduction of wave-uniform counts -> cglob ----
    auto reduce_counts = [&]() {
        if (lane == 0) {
#pragma unroll
            for (int p = 0; p < NPROBE; ++p)
                red[w * NPROBE + p] = (uint32_t)cnt[p];
        }
        __syncthreads();
        if (tid < NPROBE) {
            int s = 0;
#pragma unroll
            for (int ww = 0; ww < NT / 64; ++ww) s += (int)red[ww * NPROBE + tid];
            cglob[tid] = s;
        }
        __syncthreads();
    };
    reduce_counts();

    // ---- bracket (lo, hi]: count(>hi) < K <= count(>lo) ----
    int lo, hi, cab, cgl;  // cab = count(>hi), cgl = count(>lo)
    {
        int j = 0;
        while (j < NPROBE && cglob[j] < K_WIN) ++j;
        if (j == 0) {
            lo = P[0]; cgl = cglob[0]; hi = 65535; cab = 0;
        } else if (j == NPROBE) {
            lo = -1; cgl = N_UNITS; hi = P[NPROBE - 1]; cab = cglob[NPROBE - 1];
        } else {
            lo = P[j]; cgl = cglob[j]; hi = P[j - 1]; cab = cglob[j - 1];
        }
    }
    int m = cgl - cab;

    // ---- refinement (exact, terminates; ~never runs on benchmark data) ----
    while (m > CAP && (hi - lo) > 1) {
        __syncthreads();
        if (tid < NPROBE)
            prb[tid] = lo + (int)(((long)(hi - lo) * (NPROBE - tid)) / (NPROBE + 1));
        __syncthreads();
#pragma unroll
        for (int p = 0; p < NPROBE; ++p) P[p] = prb[p];
#pragma unroll
        for (int p = 0; p < NPROBE; ++p) cnt[p] = 0;
#pragma unroll
        for (int j = 0; j < ITERS; ++j) {
            int h0 = (int)(kh[j].x & 0xFFFFu), h1 = (int)(kh[j].x >> 16);
            int h2 = (int)(kh[j].y & 0xFFFFu), h3 = (int)(kh[j].y >> 16);
#pragma unroll
            for (int p = 0; p < NPROBE; ++p)
                cnt[p] += __popcll(__ballot(h0 > P[p])) +
                          __popcll(__ballot(h1 > P[p])) +
                          __popcll(__ballot(h2 > P[p])) +
                          __popcll(__ballot(h3 > P[p]));
        }
        reduce_counts();
        int j = 0;
        while (j < NPROBE && cglob[j] < K_WIN) ++j;
        if (j == 0) {
            lo = P[0]; cgl = cglob[0];  // hi, cab unchanged
        } else if (j == NPROBE) {
            hi = P[NPROBE - 1]; cab = cglob[NPROBE - 1];  // lo, cgl unchanged
        } else {
            lo = P[j]; cgl = cglob[j]; hi = P[j - 1]; cab = cglob[j - 1];
        }
        m = cgl - cab;
    }

    // ---- fused bulk mask write (coalesced float4) + candidate gather ----
#pragma unroll
    for (int j = 0; j < ITERS; ++j) {
        int f = tid + j * NT;
        int h0 = (int)(kh[j].x & 0xFFFFu), h1 = (int)(kh[j].x >> 16);
        int h2 = (int)(kh[j].y & 0xFFFFu), h3 = (int)(kh[j].y >> 16);
        float4 o;
        o.x = (h0 > hi) ? 1.0f : 0.0f;
        o.y = (h1 > hi) ? 1.0f : 0.0f;
        o.z = (h2 > hi) ? 1.0f : 0.0f;
        o.w = (h3 > hi) ? 1.0f : 0.0f;
        ((float4*)orow)[f] = o;
        int base = f * 4;
        int h[4] = {h0, h1, h2, h3};
#pragma unroll
        for (int e = 0; e < 4; ++e) {
            if (h[e] > lo && h[e] <= hi) {
                int p = atomicAdd(&sc[0], 1);
                if (p < CAP) cand_idx[p] = (uint32_t)(base + e);
            }
        }
    }
    __syncthreads();
    const int mm = sc[0];
    const int need = K_WIN - cab;

    // ---- fetch full keys for candidates (scattered, L2/L3-hit) ----
    const float* xr = x + (size_t)row * N_UNITS;
    const int mc = (mm <= CAP) ? mm : 0;
    for (int j = tid; j < mc; j += NT) {
        int i = (int)cand_idx[j];
        cand_key[j] = fkey(xr[i] * bf[i]);
    }
    __syncthreads();  // orders cand_key writes AND bulk global writes

    if (mm <= CAP) {
        // ---- exact rank among candidates; scatter the `need` winners ----
        // tie-break: (key desc, idx asc) = jax.lax.top_k semantics
        for (int j = tid; j < mm; j += NT) {
            uint32_t myk = cand_key[j];
            uint32_t myi = cand_idx[j];
            int r = 0;
            for (int l = 0; l < mm; ++l) {
                uint32_t lk = cand_key[l];
                r += (lk > myk) || (lk == myk && cand_idx[l] < myi);
            }
            if (r < need) orow[myi] = 1.0f;
        }
    } else if (tid == 0) {
        // Fallback (unreachable on benchmark data): > CAP ties at khi == hi.
        // Serial radix on low 16 bits of the full key; exact, index-ordered.
        uint32_t* h8 = cand_idx;  // reuse as 256-entry histogram
        for (int b = 0; b < 256; ++b) h8[b] = 0;
        for (int i = 0; i < N_UNITS; ++i) {
            uint32_t kf = fkey(xr[i] * bf[i]);
            if ((int)(kf >> 16) == hi) h8[(kf & 0xFFFFu) >> 8]++;
        }
        int acc = 0, d1 = 0, need2 = 0;
        for (int b = 255; b >= 0; --b) {
            int c = (int)h8[b];
            if (acc + c >= need) { d1 = b; need2 = need - acc; break; }
            acc += c;
        }
        for (int b = 0; b < 256; ++b) h8[b] = 0;
        for (int i = 0; i < N_UNITS; ++i) {
            uint32_t kf = fkey(xr[i] * bf[i]);
            if ((int)(kf >> 16) == hi && (int)((kf & 0xFFFFu) >> 8) == d1)
                h8[kf & 0xFFu]++;
        }
        int acc2 = 0, d2 = 0, need3 = 0;
        for (int b = 255; b >= 0; --b) {
            int c = (int)h8[b];
            if (acc2 + c >= need2) { d2 = b; need3 = need2 - acc2; break; }
            acc2 += c;
        }
        uint32_t Tlo = ((uint32_t)d1 << 8) | (uint32_t)d2;
        int r = 0;
        for (int i = 0; i < N_UNITS; ++i) {
            uint32_t kf = fkey(xr[i] * bf[i]);
            if ((int)(kf >> 16) == hi) {
                uint32_t kl = kf & 0xFFFFu;
                if (kl > Tlo) orow[i] = 1.0f;
                else if (kl == Tlo && r < need3) { orow[i] = 1.0f; ++r; }
            }
        }
    }
}

extern "C" void kernel_launch(void* const* d_in, const int* in_sizes, int n_in,
                              void* d_out, int out_size, void* d_ws,
                              size_t ws_size, hipStream_t stream) {
    const float* x = (const float*)d_in[0];
    const float* duty = (const float*)d_in[1];
    float* out = (float*)d_out;
    float* bf = (float*)d_ws;  // 16384 floats = 64 KB scratch

    hipLaunchKernelGGL(boost_kernel, dim3(N_UNITS / 256), dim3(256), 0, stream,
                       duty, bf, N_UNITS);
    int rows = out_size / N_UNITS;  // 4096
    hipLaunchKernelGGL(kwinners_kernel, dim3(rows), dim3(NT), 0, stream, x, bf,
                       out);
}